// Round 4
// baseline (9459.995 us; speedup 1.0000x reference)
//
#include <hip/hip_runtime.h>
#include <hip/hip_bf16.h>
#include <math.h>

// ---------------------------------------------------------------------------
// BigHeteroGNN — ROUND 4: runtime dtype-adaptive correctness build.
// Theory: 3 rounds of nan/inf garbage <=> dtype mismatch (f32 data read as
// bf16, or bf16 written where harness reads f32). Device-side detector picks
// the interpretation; every external load/store branches on the flag with
// element-offset addressing. Internal scratch stays canonical bf16/f32.
// Sentinels in logits: NaN->12345, inf->54321 (distinct error magnitudes).
// ---------------------------------------------------------------------------

typedef __bf16 bf16;

#define NE 200000
#define N0T 100000
#define N1T 150000
#define N2T 50000

__device__ inline float bflo(unsigned u) { return __uint_as_float(u << 16); }
__device__ inline float bfhi(unsigned u) { return __uint_as_float(u & 0xFFFF0000u); }
__device__ inline unsigned f2bfbits(float f) {
    unsigned x = __float_as_uint(f);
    return ((x + 0x7FFFu + ((x >> 16) & 1u)) >> 16) & 0xFFFFu;  // RNE
}
__device__ inline float gelu_exact(float x) {
    return 0.5f * x * (1.0f + erff(x * 0.70710678118654752f));
}

// ---------------------------------------------------------------------------
// Dtype detection: count plausible-magnitude values under both views.
// Real N(0,1)-scale data passes ~100%; random-exponent garbage ~20%.
// flag: 1 = float32, 0 = bf16.
// ---------------------------------------------------------------------------
__device__ inline int plausible(float v) {
    float a = fabsf(v);
    return (v == 0.f) || (a > 1e-8f && a < 1e8f);  // NaN/inf fail
}

__global__ void detect_k(const void* p, int* flag) {
    __shared__ int cF, cB;
    int tid = threadIdx.x;  // 256 threads
    if (tid == 0) { cF = 0; cB = 0; }
    __syncthreads();
    float vf = ((const float*)p)[tid];
    float b0 = (float)((const bf16*)p)[2 * tid];
    float b1 = (float)((const bf16*)p)[2 * tid + 1];
    if (plausible(vf)) atomicAdd(&cF, 1);
    if (plausible(b0) && plausible(b1)) atomicAdd(&cB, 1);
    __syncthreads();
    if (tid == 0) *flag = (cF > cB) ? 1 : 0;
}

// ---------------------------------------------------------------------------
// Conversions to canonical formats
// ---------------------------------------------------------------------------
__global__ void conv_bf16_k(const void* src, size_t srcOff, bf16* dst, int n,
                            const int* flagp, int use) {
    int f = use ? *flagp : 0;
    int i = blockIdx.x * 256 + threadIdx.x;
    if (i >= n) return;
    float v = f ? ((const float*)src)[srcOff + i]
                : (float)((const bf16*)src)[srcOff + i];
    dst[i] = (bf16)v;
}

__global__ void conv_f32_k(const void* src, float* dst, int n, const int* flagp) {
    int f = *flagp;
    int i = blockIdx.x * 256 + threadIdx.x;
    if (i >= n) return;
    dst[i] = f ? ((const float*)src)[i] : (float)((const bf16*)src)[i];
}

// ---------------------------------------------------------------------------
// Folded ke/ve weights, natural orientation Wf[e][kind][i][j] (canonical bf16)
// kind 0 = k-side (arel, * prel/sqrt(32)), 1 = v-side (mrel)
// ---------------------------------------------------------------------------
__global__ void prep_kv(const void* kw, const void* vw, const void* arel,
                        const void* mrel, const void* prel,
                        bf16* __restrict__ Wf, const int* fwp) {
    int fw = *fwp;
    int gid = blockIdx.x * 256 + threadIdx.x;
    if (gid >= 4 * 2 * 128 * 128) return;
    int j = gid & 127;
    int i = (gid >> 7) & 127;
    int kind = (gid >> 14) & 1;
    int e = gid >> 15;
    const int stab[4] = {1, 2, 0, 0};
    int st = stab[e];
    int h = j >> 5, jj = j & 31;
    size_t wbase = (size_t)st * 16384;
    size_t rbase = (size_t)(e * 4 + h) * 1024;
    const void* w   = kind ? vw : kw;
    const void* rel = kind ? mrel : arel;
    float acc = 0.f;
    for (int d = 0; d < 32; ++d) {
        size_t wi = wbase + (size_t)i * 128 + h * 32 + d;
        size_t ri = rbase + (size_t)d * 32 + jj;
        float wv = fw ? ((const float*)w)[wi]   : (float)((const bf16*)w)[wi];
        float rv = fw ? ((const float*)rel)[ri] : (float)((const bf16*)rel)[ri];
        acc += wv * rv;
    }
    if (!kind) {
        float pv = fw ? ((const float*)prel)[e * 4 + h]
                      : (float)((const bf16*)prel)[e * 4 + h];
        acc *= pv * 0.17677669529663687f;  // 1/sqrt(32)
    }
    Wf[((size_t)(e * 2 + kind) * 128 + i) * 128 + j] = (bf16)acc;
}

__global__ void prep_kvbias(const void* kb, const void* vb, const void* arel,
                            const void* mrel, const void* prel,
                            float* __restrict__ Bf, const int* fwp) {
    int fw = *fwp;
    int gid = blockIdx.x * 256 + threadIdx.x;
    if (gid >= 4 * 2 * 128) return;
    int j = gid & 127;
    int kind = (gid >> 7) & 1;
    int e = gid >> 8;
    const int stab[4] = {1, 2, 0, 0};
    int st = stab[e];
    int h = j >> 5, jj = j & 31;
    size_t bbase = (size_t)st * 128;
    size_t rbase = (size_t)(e * 4 + h) * 1024;
    const void* b   = kind ? vb : kb;
    const void* rel = kind ? mrel : arel;
    float acc = 0.f;
    for (int d = 0; d < 32; ++d) {
        size_t bi = bbase + h * 32 + d;
        size_t ri = rbase + (size_t)d * 32 + jj;
        float bv = fw ? ((const float*)b)[bi]   : (float)((const bf16*)b)[bi];
        float rv = fw ? ((const float*)rel)[ri] : (float)((const bf16*)rel)[ri];
        acc += bv * rv;
    }
    if (!kind) {
        float pv = fw ? ((const float*)prel)[e * 4 + h]
                      : (float)((const bf16*)prel)[e * 4 + h];
        acc *= pv * 0.17677669529663687f;
    }
    Bf[gid] = acc;
}

// ---------------------------------------------------------------------------
// CSR build (per dst type); adjacency stores ALPHA slot ids.
// ---------------------------------------------------------------------------
__global__ void zero_i32(int* p, int n) {
    int i = blockIdx.x * 256 + threadIdx.x;
    if (i < n) p[i] = 0;
}

__global__ void hist_k(const int* __restrict__ e0, const int* __restrict__ e1,
                       const int* __restrict__ e2, const int* __restrict__ e3,
                       int* c0, int* c1, int* c2) {
    int gid = blockIdx.x * 256 + threadIdx.x;
    if (gid >= 4 * NE) return;
    int e = gid / NE, i = gid - e * NE;
    const int* ep = (e == 0) ? e0 : (e == 1) ? e1 : (e == 2) ? e2 : e3;
    int dst = ep[NE + i];
    int* c = (e < 2) ? c0 : (e == 2) ? c1 : c2;
    atomicAdd(&c[dst], 1);
}

__global__ __launch_bounds__(256) void scan1(const int* __restrict__ cnt, int n,
                                             int* __restrict__ excl, int* __restrict__ bsums) {
    __shared__ int s[256];
    int tid = threadIdx.x;
    int base = blockIdx.x * 2048 + tid * 8;
    int v[8]; int tsum = 0;
    for (int j = 0; j < 8; ++j) {
        int idx = base + j;
        int c = (idx < n) ? cnt[idx] : 0;
        v[j] = c; tsum += c;
    }
    s[tid] = tsum; __syncthreads();
    for (int off = 1; off < 256; off <<= 1) {
        int t = 0; if (tid >= off) t = s[tid - off];
        __syncthreads(); s[tid] += t; __syncthreads();
    }
    int run = s[tid] - tsum;
    for (int j = 0; j < 8; ++j) {
        int idx = base + j;
        if (idx < n) excl[idx] = run;
        run += v[j];
    }
    if (tid == 255) bsums[blockIdx.x] = s[255];
}

__global__ void scan2(int* __restrict__ bs, int nb) {
    __shared__ int s[256];
    int tid = threadIdx.x;
    int v = (tid < nb) ? bs[tid] : 0;
    s[tid] = v; __syncthreads();
    for (int off = 1; off < 256; off <<= 1) {
        int t = 0; if (tid >= off) t = s[tid - off];
        __syncthreads(); s[tid] += t; __syncthreads();
    }
    if (tid < nb) bs[tid] = s[tid] - v;
}

__global__ void scan3(int* __restrict__ excl, const int* __restrict__ bs,
                      int* __restrict__ cursor, int n, int total) {
    int idx = blockIdx.x * 256 + threadIdx.x;
    if (idx < n) {
        int v = excl[idx] + bs[idx >> 11];
        excl[idx] = v;
        cursor[idx] = v;
    }
    if (idx == 0) excl[n] = total;
}

__global__ void fill_k(const int* __restrict__ e0, const int* __restrict__ e1,
                       const int* __restrict__ e2, const int* __restrict__ e3,
                       int* c0, int* c1, int* c2,
                       unsigned* a0, unsigned* a1, unsigned* a2) {
    int gid = blockIdx.x * 256 + threadIdx.x;
    if (gid >= 4 * NE) return;
    int e = gid / NE, i = gid - e * NE;
    const int* ep = (e == 0) ? e0 : (e == 1) ? e1 : (e == 2) ? e2 : e3;
    int dst = ep[NE + i];
    const int slotbase[4] = {0, 200000, 0, 0};
    int* c; unsigned* a;
    if (e < 2)      { c = c0; a = a0; }
    else if (e == 2){ c = c1; a = a1; }
    else            { c = c2; a = a2; }
    int pos = atomicAdd(&c[dst], 1);
    a[pos] = (unsigned)(slotbase[e] + i);
}

// ---------------------------------------------------------------------------
// GEMV: out[n,col] = A[n,:] @ W[:,col] + bias[col]
// mode 1: v = s*v + (1-s)*xres; relu.  Flagged external pointers carry
// element offsets (dtype-dependent byte addressing resolved in-kernel).
// ---------------------------------------------------------------------------
__global__ __launch_bounds__(256) void gemv128(
    const void* A, size_t aOff, int aUse, int nrows,
    const bf16* __restrict__ W, const float* __restrict__ bias,
    void* out, size_t outOff, int outUse, int mode,
    const void* xres, size_t xrOff, const float* skipv, const int* fxp) {
    int fx = *fxp;
    int fA = aUse ? fx : 0;
    int gid = blockIdx.x * 256 + threadIdx.x;
    int n = gid >> 7, col = gid & 127;
    if (n >= nrows) return;
    size_t rb = (size_t)n * 128;
    float acc = 0.f;
    if (fA) {
        const float* ar = (const float*)A + aOff + rb;
        for (int i = 0; i < 128; ++i) acc += ar[i] * (float)W[i * 128 + col];
    } else {
        const bf16* ar = (const bf16*)A + aOff + rb;
        for (int i = 0; i < 128; ++i) acc += (float)ar[i] * (float)W[i * 128 + col];
    }
    acc += bias[col];
    if (mode == 1) {
        float s = 1.f / (1.f + __expf(-skipv[0]));
        size_t xi = xrOff + rb + col;
        float xr = fx ? ((const float*)xres)[xi] : (float)((const bf16*)xres)[xi];
        acc = s * acc + (1.f - s) * xr;
        acc = fmaxf(acc, 0.f);
    }
    int fo = outUse ? fx : 0;
    size_t oi = outOff + rb + col;
    if (fo) ((float*)out)[oi] = acc; else ((bf16*)out)[oi] = (bf16)acc;
}

// ---------------------------------------------------------------------------
// Pass 1: per-edge alpha. One wave/edge; lane -> 2 dims; head = lane>>4.
// ---------------------------------------------------------------------------
__global__ __launch_bounds__(256) void pass1_alpha(
    const int* __restrict__ ei, int slotBase,
    const bf16* __restrict__ Wk, const float* __restrict__ Bk,
    const void* X, size_t xOff, int xUse, const int* fxp,
    const bf16* __restrict__ QB, float* __restrict__ ALPHA) {
    int fX = xUse ? *fxp : 0;
    int lane = threadIdx.x & 63;
    int e = blockIdx.x * 4 + (threadIdx.x >> 6);
    if (e >= NE) return;
    int src = ei[e], dst = ei[NE + e];
    int j0 = lane * 2;
    size_t xb = xOff + (size_t)src * 128;
    float xa_l, xb_l;
    if (fX) { xa_l = ((const float*)X)[xb + j0]; xb_l = ((const float*)X)[xb + j0 + 1]; }
    else    { xa_l = (float)((const bf16*)X)[xb + j0]; xb_l = (float)((const bf16*)X)[xb + j0 + 1]; }
    float k0 = Bk[j0], k1 = Bk[j0 + 1];
    for (int ii = 0; ii < 64; ++ii) {
        float xa = __shfl(xa_l, ii), xbv = __shfl(xb_l, ii);
        unsigned wa = *(const unsigned*)(Wk + (size_t)(2 * ii) * 128 + j0);
        unsigned wb = *(const unsigned*)(Wk + (size_t)(2 * ii + 1) * 128 + j0);
        k0 += xa * bflo(wa) + xbv * bflo(wb);
        k1 += xa * bfhi(wa) + xbv * bfhi(wb);
    }
    unsigned qv = *(const unsigned*)(QB + (size_t)dst * 128 + j0);
    float part = bflo(qv) * k0 + bfhi(qv) * k1;
    part += __shfl_xor(part, 1);
    part += __shfl_xor(part, 2);
    part += __shfl_xor(part, 4);
    part += __shfl_xor(part, 8);
    if ((lane & 15) == 0)
        ALPHA[(size_t)(slotBase + e) * 4 + (lane >> 4)] = part;
}

// ---------------------------------------------------------------------------
// Pass 2: per-node softmax + weighted on-the-fly ve aggregation + gelu.
// ---------------------------------------------------------------------------
__global__ __launch_bounds__(256) void pass2_agg(
    const int* __restrict__ rp, const unsigned* __restrict__ adj,
    const float* __restrict__ ALPHA,
    const int* __restrict__ eiA, const int* __restrict__ eiB, int split,
    const bf16* __restrict__ WvA, const bf16* __restrict__ WvB,
    const float* __restrict__ BvA, const float* __restrict__ BvB,
    const void* XA, size_t aOffX, int aUse,
    const void* XB, size_t bOffX, int bUse,
    const int* fxp, bf16* __restrict__ G, int n) {
    int fx = *fxp;
    int fA = aUse ? fx : 0, fB = bUse ? fx : 0;
    int lane = threadIdx.x & 63;
    int node = blockIdx.x * 4 + (threadIdx.x >> 6);
    if (node >= n) return;
    int beg = rp[node], end = rp[node + 1];
    int h = lane >> 4;
    float m = -3.4e38f, l = 0.f;
    for (int i = beg; i < end; ++i) {
        float a = ALPHA[(size_t)adj[i] * 4 + h];
        float nm = fmaxf(m, a);
        l = l * __expf(m - nm) + __expf(a - nm);
        m = nm;
    }
    float invl = (end > beg) ? 1.f / l : 0.f;
    int j0 = lane * 2;
    float acc0 = 0.f, acc1 = 0.f;
    for (int i = beg; i < end; ++i) {
        int slot = (int)adj[i];
        float w = __expf(ALPHA[(size_t)slot * 4 + h] - m) * invl;
        bool isB = slot >= split;
        int eidx = isB ? slot - split : slot;
        const int*   ei = isB ? eiB : eiA;
        const bf16*  Wv = isB ? WvB : WvA;
        const float* Bv = isB ? BvB : BvA;
        const void*  X  = isB ? XB  : XA;
        size_t xo = isB ? bOffX : aOffX;
        int fX = isB ? fB : fA;
        int src = ei[eidx];
        size_t xb = xo + (size_t)src * 128;
        float xa_l, xb_l;
        if (fX) { xa_l = ((const float*)X)[xb + j0]; xb_l = ((const float*)X)[xb + j0 + 1]; }
        else    { xa_l = (float)((const bf16*)X)[xb + j0]; xb_l = (float)((const bf16*)X)[xb + j0 + 1]; }
        float v0 = Bv[j0], v1 = Bv[j0 + 1];
        for (int ii = 0; ii < 64; ++ii) {
            float xa = __shfl(xa_l, ii), xbv = __shfl(xb_l, ii);
            unsigned wa = *(const unsigned*)(Wv + (size_t)(2 * ii) * 128 + j0);
            unsigned wb = *(const unsigned*)(Wv + (size_t)(2 * ii + 1) * 128 + j0);
            v0 += xa * bflo(wa) + xbv * bflo(wb);
            v1 += xa * bfhi(wa) + xbv * bfhi(wb);
        }
        acc0 += w * v0;
        acc1 += w * v1;
    }
    float g0 = gelu_exact(acc0), g1 = gelu_exact(acc1);
    *(unsigned*)(G + (size_t)node * 128 + j0) = f2bfbits(g0) | (f2bfbits(g1) << 16);
}

// ---------------------------------------------------------------------------
// Logits + sentinels: NaN -> 12345, inf -> 54321 (diagnostic magnitudes)
// ---------------------------------------------------------------------------
__global__ __launch_bounds__(256) void logits_k(
    const void* X, size_t xOff, const float* __restrict__ W,
    const float* __restrict__ B, void* out, int n, const int* fxp) {
    int fx = *fxp;
    int lane = threadIdx.x & 63;
    int node = blockIdx.x * 4 + (threadIdx.x >> 6);
    if (node >= n) return;
    size_t xb = xOff + (size_t)node * 128;
    int d0 = lane * 2;
    float x0, x1;
    if (fx) { x0 = ((const float*)X)[xb + d0]; x1 = ((const float*)X)[xb + d0 + 1]; }
    else    { x0 = (float)((const bf16*)X)[xb + d0]; x1 = (float)((const bf16*)X)[xb + d0 + 1]; }
    float p0 = x0 * W[d0 * 3 + 0] + x1 * W[d0 * 3 + 3];
    float p1 = x0 * W[d0 * 3 + 1] + x1 * W[d0 * 3 + 4];
    float p2 = x0 * W[d0 * 3 + 2] + x1 * W[d0 * 3 + 5];
    for (int off = 1; off < 64; off <<= 1) {
        p0 += __shfl_xor(p0, off);
        p1 += __shfl_xor(p1, off);
        p2 += __shfl_xor(p2, off);
    }
    if (lane == 0) {
        p0 += B[0]; p1 += B[1]; p2 += B[2];
        if (p0 != p0) p0 = 12345.f; else if (fabsf(p0) > 1e30f) p0 = 54321.f;
        if (p1 != p1) p1 = 12345.f; else if (fabsf(p1) > 1e30f) p1 = 54321.f;
        if (p2 != p2) p2 = 12345.f; else if (fabsf(p2) > 1e30f) p2 = 54321.f;
        size_t ob = (size_t)node * 3;
        if (fx) {
            ((float*)out)[ob + 0] = p0; ((float*)out)[ob + 1] = p1; ((float*)out)[ob + 2] = p2;
        } else {
            ((bf16*)out)[ob + 0] = (bf16)p0; ((bf16*)out)[ob + 1] = (bf16)p1; ((bf16*)out)[ob + 2] = (bf16)p2;
        }
    }
}

// ---------------------------------------------------------------------------

extern "C" void kernel_launch(void* const* d_in, const int* in_sizes, int n_in,
                              void* d_out, int out_size, void* d_ws, size_t ws_size,
                              hipStream_t stream) {
    (void)n_in; (void)out_size; (void)ws_size;

    const void* x_in[3] = {d_in[0], d_in[1], d_in[2]};
    const int* ei[4] = {(const int*)d_in[3], (const int*)d_in[4],
                        (const int*)d_in[5], (const int*)d_in[6]};

    // ---- workspace carve (~78 MB) ----
    char* p = (char*)d_ws;
    auto alloc = [&](size_t b) { char* r = p; p += (b + 255) & ~(size_t)255; return r; };
    bf16*  QB    = (bf16*)alloc(150000ull * 128 * 2);   // Q then G, per dst type
    bf16*  XOLD  = (bf16*)alloc(100000ull * 128 * 2);   // canonical-bf16 x0 for this layer
    float* ALPHA = (float*)alloc(400000ull * 4 * 4);
    bf16*  Wfold = (bf16*)alloc(2ull * 8 * 16384 * 2);
    float* Bfold = (float*)alloc(2ull * 8 * 128 * 4);
    bf16*  qwC   = (bf16*)alloc(2ull * 3 * 16384 * 2);
    bf16*  awC   = (bf16*)alloc(2ull * 3 * 16384 * 2);
    float* qbC   = (float*)alloc(2ull * 384 * 4);
    float* abC   = (float*)alloc(2ull * 384 * 4);
    float* skipC = (float*)alloc(2ull * 3 * 4);
    float* linwC = (float*)alloc(384ull * 4);
    float* linbC = (float*)alloc(3ull * 4);
    int*   flags = (int*)alloc(2ull * 4);               // [0]=fx, [1]=fw
    int* counts  = (int*)alloc(300000ull * 4);
    int* rowptr  = (int*)alloc(300003ull * 4);
    int* cursor  = (int*)alloc(300000ull * 4);
    unsigned* adj = (unsigned*)alloc(800000ull * 4);
    int* bsum    = (int*)alloc(3ull * 256 * 4);

    int* fxp = flags;      // x / outputs dtype
    int* fwp = flags + 1;  // weights dtype

    const int Ns[3]  = {N0T, N1T, N2T};
    const int tot[3] = {400000, 200000, 200000};
    int* cn[3] = {counts, counts + 100000, counts + 250000};
    int* rp[3] = {rowptr, rowptr + 100001, rowptr + 250002};
    int* cu[3] = {cursor, cursor + 100000, cursor + 250000};
    unsigned* aj[3] = {adj, adj + 400000, adj + 600000};
    const size_t dxsOff[3] = {300000ull, 13100000ull, 32300000ull};

    // ---- dtype detection ----
    detect_k<<<1, 256, 0, stream>>>(d_in[0], fxp);
    detect_k<<<1, 256, 0, stream>>>(d_in[7], fwp);

    // ---- adaptive input indexing (dict vs signature order) ----
    int i_qw[2], i_qb[2], i_aw[2], i_ab[2], i_skip[2];
    for (int L = 0; L < 2; ++L) {
        int b = 7 + 12 * L;
        bool sig = (in_sizes[b + 1] == 384);  // sig: kw,kb,qw,qb,vw,vb,aw,ab
        int ikw, ivw, ikb, ivb;
        if (sig) { ikw = b; ikb = b + 1; i_qw[L] = b + 2; i_qb[L] = b + 3;
                   ivw = b + 4; ivb = b + 5; i_aw[L] = b + 6; i_ab[L] = b + 7; }
        else     { ikw = b; i_qw[L] = b + 1; ivw = b + 2; i_aw[L] = b + 3;
                   ikb = b + 4; i_qb[L] = b + 5; ivb = b + 6; i_ab[L] = b + 7; }
        i_skip[L] = b + 11;
        // canonical copies of q/a weights+biases, skip
        conv_bf16_k<<<192, 256, 0, stream>>>(d_in[i_qw[L]], 0, qwC + (size_t)L * 49152, 49152, fwp, 1);
        conv_bf16_k<<<192, 256, 0, stream>>>(d_in[i_aw[L]], 0, awC + (size_t)L * 49152, 49152, fwp, 1);
        conv_f32_k<<<2, 256, 0, stream>>>(d_in[i_qb[L]], qbC + L * 384, 384, fwp);
        conv_f32_k<<<2, 256, 0, stream>>>(d_in[i_ab[L]], abC + L * 384, 384, fwp);
        conv_f32_k<<<1, 256, 0, stream>>>(d_in[i_skip[L]], skipC + L * 3, 3, fwp);
        // folded k/v weights + biases
        prep_kv<<<512, 256, 0, stream>>>(d_in[ikw], d_in[ivw], d_in[b + 8], d_in[b + 9],
                                         d_in[b + 10], Wfold + (size_t)L * 8 * 16384, fwp);
        prep_kvbias<<<4, 256, 0, stream>>>(d_in[ikb], d_in[ivb], d_in[b + 8], d_in[b + 9],
                                           d_in[b + 10], Bfold + (size_t)L * 1024, fwp);
    }
    conv_f32_k<<<2, 256, 0, stream>>>(d_in[31], linwC, 384, fwp);
    conv_f32_k<<<1, 256, 0, stream>>>(d_in[32], linbC, 3, fwp);

    // ---- CSR build ----
    zero_i32<<<1172, 256, 0, stream>>>(counts, 300000);
    hist_k<<<3125, 256, 0, stream>>>(ei[0], ei[1], ei[2], ei[3], cn[0], cn[1], cn[2]);
    for (int t = 0; t < 3; ++t) {
        int nb = (Ns[t] + 2047) / 2048;
        scan1<<<nb, 256, 0, stream>>>(cn[t], Ns[t], rp[t], bsum + t * 256);
        scan2<<<1, 256, 0, stream>>>(bsum + t * 256, nb);
        scan3<<<(Ns[t] + 255) / 256, 256, 0, stream>>>(rp[t], bsum + t * 256, cu[t], Ns[t], tot[t]);
    }
    fill_k<<<3125, 256, 0, stream>>>(ei[0], ei[1], ei[2], ei[3],
                                     cu[0], cu[1], cu[2], aj[0], aj[1], aj[2]);

    // ---- two HGT layers, per-dst-type sequential ----
    for (int L = 0; L < 2; ++L) {
        bf16*  WfL = Wfold + (size_t)L * 8 * 16384;
        float* BfL = Bfold + (size_t)L * 1024;
        auto Wk = [&](int e) { return WfL + (size_t)(e * 2 + 0) * 16384; };
        auto Wv = [&](int e) { return WfL + (size_t)(e * 2 + 1) * 16384; };
        auto Bk = [&](int e) { return BfL + (e * 2 + 0) * 128; };
        auto Bv = [&](int e) { return BfL + (e * 2 + 1) * 128; };

        // x inputs this layer: L=0 -> d_in x's (offset 0); L=1 -> dxs in d_out
        const void* xp[3]; size_t xo[3];
        for (int t = 0; t < 3; ++t) {
            xp[t] = L ? (const void*)d_out : x_in[t];
            xo[t] = L ? dxsOff[t] : 0;
        }

        // canonical-bf16 snapshot of this layer's x0 (read by dst types 1,2)
        conv_bf16_k<<<50000, 256, 0, stream>>>(xp[0], xo[0], XOLD, 12800000, fxp, 1);

        for (int t = 0; t < 3; ++t) {
            // Q projection for dst type t -> QB (internal bf16)
            gemv128<<<(Ns[t] * 128 + 255) / 256, 256, 0, stream>>>(
                xp[t], xo[t], 1, Ns[t],
                qwC + ((size_t)L * 3 + t) * 16384, qbC + L * 384 + t * 128,
                QB, 0, 0, 0, nullptr, 0, nullptr, fxp);

            // pass 1: alpha for all incoming edges
            if (t == 0) {
                pass1_alpha<<<50000, 256, 0, stream>>>(ei[0], 0,      Wk(0), Bk(0),
                                                       xp[1], xo[1], 1, fxp, QB, ALPHA);
                pass1_alpha<<<50000, 256, 0, stream>>>(ei[1], 200000, Wk(1), Bk(1),
                                                       xp[2], xo[2], 1, fxp, QB, ALPHA);
            } else {
                int e = (t == 1) ? 2 : 3;
                pass1_alpha<<<50000, 256, 0, stream>>>(ei[e], 0, Wk(e), Bk(e),
                                                       XOLD, 0, 0, fxp, QB, ALPHA);
            }

            // pass 2: softmax + aggregation + gelu -> QB (overwrite)
            if (t == 0) {
                pass2_agg<<<(N0T + 3) / 4, 256, 0, stream>>>(
                    rp[0], aj[0], ALPHA, ei[0], ei[1], 200000,
                    Wv(0), Wv(1), Bv(0), Bv(1),
                    xp[1], xo[1], 1, xp[2], xo[2], 1, fxp, QB, N0T);
            } else {
                int e = (t == 1) ? 2 : 3;
                pass2_agg<<<(Ns[t] + 3) / 4, 256, 0, stream>>>(
                    rp[t], aj[t], ALPHA, ei[e], ei[e], 0x40000000,
                    Wv(e), Wv(e), Bv(e), Bv(e),
                    XOLD, 0, 0, XOLD, 0, 0, fxp, QB, Ns[t]);
            }

            // output projection + skip + relu -> dxs[t] (in d_out)
            gemv128<<<(Ns[t] * 128 + 255) / 256, 256, 0, stream>>>(
                QB, 0, 0, Ns[t],
                awC + ((size_t)L * 3 + t) * 16384, abC + L * 384 + t * 128,
                d_out, dxsOff[t], 1, 1, xp[t], xo[t], skipC + L * 3 + t, fxp);
        }
    }

    // ---- logits head ----
    logits_k<<<25000, 256, 0, stream>>>(d_out, dxsOff[0], linwC, linbC, d_out, N0T, fxp);
}

// Round 5
// 1752.747 us; speedup vs baseline: 5.3972x; 5.3972x over previous
//
#include <hip/hip_runtime.h>
#include <hip/hip_bf16.h>
#include <math.h>

// ---------------------------------------------------------------------------
// BigHeteroGNN — ROUND 5: MFMA fast path + runtime dtype adaptivity (R4).
// K/V per (edge-type, src-node) precomputed by MFMA GEMM with folded
// rel-matrices; edge_agg = 512B-row gather + online softmax (no per-edge
// GEMV). ~187MB workspace. External loads/stores branch on detected dtype.
// ---------------------------------------------------------------------------

typedef __bf16 bf16;
typedef __bf16 bf16x8 __attribute__((ext_vector_type(8)));
typedef float  f32x4  __attribute__((ext_vector_type(4)));

#define NE 200000
#define N0T 100000
#define N1T 150000
#define N2T 50000
#define BPITCH 136

__device__ inline float bflo(unsigned u) { return __uint_as_float(u << 16); }
__device__ inline float bfhi(unsigned u) { return __uint_as_float(u & 0xFFFF0000u); }
__device__ inline unsigned f2bfbits(float f) {
    unsigned x = __float_as_uint(f);
    return ((x + 0x7FFFu + ((x >> 16) & 1u)) >> 16) & 0xFFFFu;  // RNE
}
__device__ inline float gelu_exact(float x) {
    return 0.5f * x * (1.0f + erff(x * 0.70710678118654752f));
}
__device__ inline float ldx(const void* p, size_t i, int f) {
    return f ? ((const float*)p)[i] : (float)((const bf16*)p)[i];
}

// ---------------------------------------------------------------------------
// Dtype detection (validated R4): 1 = float32, 0 = bf16.
// ---------------------------------------------------------------------------
__device__ inline int plausible(float v) {
    float a = fabsf(v);
    return (v == 0.f) || (a > 1e-8f && a < 1e8f);
}

__global__ void detect_k(const void* p, int* flag) {
    __shared__ int cF, cB;
    int tid = threadIdx.x;
    if (tid == 0) { cF = 0; cB = 0; }
    __syncthreads();
    float vf = ((const float*)p)[tid];
    float b0 = (float)((const bf16*)p)[2 * tid];
    float b1 = (float)((const bf16*)p)[2 * tid + 1];
    if (plausible(vf)) atomicAdd(&cF, 1);
    if (plausible(b0) && plausible(b1)) atomicAdd(&cB, 1);
    __syncthreads();
    if (tid == 0) *flag = (cF > cB) ? 1 : 0;
}

__global__ void conv_f32_k(const void* src, float* dst, int n, const int* flagp) {
    int f = *flagp;
    int i = blockIdx.x * 256 + threadIdx.x;
    if (i >= n) return;
    dst[i] = ldx(src, i, f);
}

// ---------------------------------------------------------------------------
// Weight prep (canonical bf16, TRANSPOSED for GEMM B-staging: WT[col][k])
// ---------------------------------------------------------------------------
__global__ void transpose128f(const void* W, bf16* __restrict__ WT, const int* fwp) {
    int fw = *fwp;
    int gid = blockIdx.x * 256 + threadIdx.x;
    if (gid >= 3 * 16384) return;
    int t = gid >> 14, r = (gid >> 7) & 127, c = gid & 127;
    WT[gid] = (bf16)ldx(W, (size_t)(t << 14) + c * 128 + r, fw);
}

// WkvT[e][kind][j][i] = (w @ blockdiag(rel))[i][j]; kind0=k(arel*prel/sqrt d),1=v(mrel)
__global__ void prep_kv(const void* kw, const void* vw, const void* arel,
                        const void* mrel, const void* prel,
                        bf16* __restrict__ WkvT, const int* fwp) {
    int fw = *fwp;
    int gid = blockIdx.x * 256 + threadIdx.x;
    if (gid >= 4 * 2 * 128 * 128) return;
    int i = gid & 127;
    int j = (gid >> 7) & 127;
    int kind = (gid >> 14) & 1;
    int e = gid >> 15;
    const int stab[4] = {1, 2, 0, 0};
    int st = stab[e];
    int h = j >> 5, jj = j & 31;
    size_t wbase = (size_t)st * 16384;
    size_t rbase = (size_t)(e * 4 + h) * 1024;
    const void* w   = kind ? vw : kw;
    const void* rel = kind ? mrel : arel;
    float acc = 0.f;
    for (int d = 0; d < 32; ++d)
        acc += ldx(w, wbase + (size_t)i * 128 + h * 32 + d, fw) *
               ldx(rel, rbase + (size_t)d * 32 + jj, fw);
    if (!kind)
        acc *= ldx(prel, e * 4 + h, fw) * 0.17677669529663687f;  // 1/sqrt(32)
    WkvT[((size_t)(e * 2 + kind) * 128 + j) * 128 + i] = (bf16)acc;
}

__global__ void prep_kvbias(const void* kb, const void* vb, const void* arel,
                            const void* mrel, const void* prel,
                            float* __restrict__ Bf, const int* fwp) {
    int fw = *fwp;
    int gid = blockIdx.x * 256 + threadIdx.x;
    if (gid >= 4 * 2 * 128) return;
    int j = gid & 127;
    int kind = (gid >> 7) & 1;
    int e = gid >> 8;
    const int stab[4] = {1, 2, 0, 0};
    int st = stab[e];
    int h = j >> 5, jj = j & 31;
    const void* b   = kind ? vb : kb;
    const void* rel = kind ? mrel : arel;
    float acc = 0.f;
    for (int d = 0; d < 32; ++d)
        acc += ldx(b, (size_t)st * 128 + h * 32 + d, fw) *
               ldx(rel, (size_t)(e * 4 + h) * 1024 + (size_t)d * 32 + jj, fw);
    if (!kind)
        acc *= ldx(prel, e * 4 + h, fw) * 0.17677669529663687f;
    Bf[gid] = acc;
}

// ---------------------------------------------------------------------------
// CSR build (per dst type). Adjacency stores KEVE-buffer-LOCAL row ids:
// e0 -> src, e1 -> 150000+src, e2 -> src, e3 -> src.
// ---------------------------------------------------------------------------
__global__ void zero_i32(int* p, int n) {
    int i = blockIdx.x * 256 + threadIdx.x;
    if (i < n) p[i] = 0;
}

__global__ void hist_k(const int* __restrict__ e0, const int* __restrict__ e1,
                       const int* __restrict__ e2, const int* __restrict__ e3,
                       int* c0, int* c1, int* c2) {
    int gid = blockIdx.x * 256 + threadIdx.x;
    if (gid >= 4 * NE) return;
    int e = gid / NE, i = gid - e * NE;
    const int* ep = (e == 0) ? e0 : (e == 1) ? e1 : (e == 2) ? e2 : e3;
    int dst = ep[NE + i];
    int* c = (e < 2) ? c0 : (e == 2) ? c1 : c2;
    atomicAdd(&c[dst], 1);
}

__global__ __launch_bounds__(256) void scan1(const int* __restrict__ cnt, int n,
                                             int* __restrict__ excl, int* __restrict__ bsums) {
    __shared__ int s[256];
    int tid = threadIdx.x;
    int base = blockIdx.x * 2048 + tid * 8;
    int v[8]; int tsum = 0;
    for (int j = 0; j < 8; ++j) {
        int idx = base + j;
        int c = (idx < n) ? cnt[idx] : 0;
        v[j] = c; tsum += c;
    }
    s[tid] = tsum; __syncthreads();
    for (int off = 1; off < 256; off <<= 1) {
        int t = 0; if (tid >= off) t = s[tid - off];
        __syncthreads(); s[tid] += t; __syncthreads();
    }
    int run = s[tid] - tsum;
    for (int j = 0; j < 8; ++j) {
        int idx = base + j;
        if (idx < n) excl[idx] = run;
        run += v[j];
    }
    if (tid == 255) bsums[blockIdx.x] = s[255];
}

__global__ void scan2(int* __restrict__ bs, int nb) {
    __shared__ int s[256];
    int tid = threadIdx.x;
    int v = (tid < nb) ? bs[tid] : 0;
    s[tid] = v; __syncthreads();
    for (int off = 1; off < 256; off <<= 1) {
        int t = 0; if (tid >= off) t = s[tid - off];
        __syncthreads(); s[tid] += t; __syncthreads();
    }
    if (tid < nb) bs[tid] = s[tid] - v;
}

__global__ void scan3(int* __restrict__ excl, const int* __restrict__ bs,
                      int* __restrict__ cursor, int n, int total) {
    int idx = blockIdx.x * 256 + threadIdx.x;
    if (idx < n) {
        int v = excl[idx] + bs[idx >> 11];
        excl[idx] = v;
        cursor[idx] = v;
    }
    if (idx == 0) excl[n] = total;
}

__global__ void fill_k(const int* __restrict__ e0, const int* __restrict__ e1,
                       const int* __restrict__ e2, const int* __restrict__ e3,
                       int* c0, int* c1, int* c2,
                       unsigned* a0, unsigned* a1, unsigned* a2) {
    int gid = blockIdx.x * 256 + threadIdx.x;
    if (gid >= 4 * NE) return;
    int e = gid / NE, i = gid - e * NE;
    const int* ep = (e == 0) ? e0 : (e == 1) ? e1 : (e == 2) ? e2 : e3;
    int src = ep[i], dst = ep[NE + i];
    const int lbase[4] = {0, 150000, 0, 0};
    int* c; unsigned* a;
    if (e < 2)      { c = c0; a = a0; }
    else if (e == 2){ c = c1; a = a1; }
    else            { c = c2; a = a2; }
    int pos = atomicAdd(&c[dst], 1);
    a[pos] = (unsigned)(lbase[e] + src);
}

// ---------------------------------------------------------------------------
// MFMA GEMM: out[n, pitch] = A[n,128] @ W + bias, W staged as WT[col][k].
// aExt/outExt: pointer uses harness dtype (branch on *fxp) vs canonical bf16.
// mode 1: v = s*(acc+bias) + (1-s)*xres[row,col]; relu. (in-place safe)
// ---------------------------------------------------------------------------
__global__ __launch_bounds__(256) void gemm128(
    const void* A, size_t aOff, int aExt, int nrows,
    const bf16* __restrict__ WT, const float* __restrict__ bias,
    void* out, size_t outOff, int outPitch, int outExt, int mode,
    const void* xres, size_t xrOff, const float* skipv, const int* fxp) {
    int fx = *fxp;
    int fA = aExt ? fx : 0;
    int fO = outExt ? fx : 0;
    __shared__ bf16 sB[128 * BPITCH];
    int tid = threadIdx.x;
    for (int it = 0; it < 8; ++it) {
        int idx = it * 256 + tid;
        int r = idx >> 4, c8 = idx & 15;
        *(bf16x8*)(&sB[r * BPITCH + c8 * 8]) = *(const bf16x8*)(WT + r * 128 + c8 * 8);
    }
    __syncthreads();

    int lane = tid & 63;
    int wave = tid >> 6;
    int quad = lane >> 4, n16 = lane & 15;
    long rbase = (long)blockIdx.x * 64 + wave * 16;
    long arow = rbase + n16;
    if (arow >= nrows) arow = nrows - 1;   // clamp; stores predicated

    bf16x8 afr[4];
    size_t abase = aOff + (size_t)arow * 128 + quad * 8;
    if (fA) {
        const float* ap = (const float*)A + abase;
        for (int k = 0; k < 4; ++k) {
            float4 u = *(const float4*)(ap + k * 32);
            float4 v = *(const float4*)(ap + k * 32 + 4);
            bf16x8 t;
            t[0] = (bf16)u.x; t[1] = (bf16)u.y; t[2] = (bf16)u.z; t[3] = (bf16)u.w;
            t[4] = (bf16)v.x; t[5] = (bf16)v.y; t[6] = (bf16)v.z; t[7] = (bf16)v.w;
            afr[k] = t;
        }
    } else {
        const bf16* ap = (const bf16*)A + abase;
        afr[0] = *(const bf16x8*)(ap);
        afr[1] = *(const bf16x8*)(ap + 32);
        afr[2] = *(const bf16x8*)(ap + 64);
        afr[3] = *(const bf16x8*)(ap + 96);
    }

    float s = 0.f, os = 0.f;
    if (mode == 1) {
        float sk = skipv[0];
        s = 1.f / (1.f + __expf(-sk));
        os = 1.f - s;
    }

    for (int c = 0; c < 8; ++c) {
        f32x4 acc = {0.f, 0.f, 0.f, 0.f};
        const bf16* bp = &sB[(c * 16 + n16) * BPITCH + quad * 8];
        for (int k = 0; k < 4; ++k)
            acc = __builtin_amdgcn_mfma_f32_16x16x32_bf16(
                afr[k], *(const bf16x8*)(bp + k * 32), acc, 0, 0, 0);
        int col = c * 16 + n16;
        float bb = bias[col];
        for (int r = 0; r < 4; ++r) {
            long row = rbase + quad * 4 + r;
            if (row < nrows) {
                float v = acc[r] + bb;
                if (mode == 1) {
                    size_t xi = xrOff + (size_t)row * 128 + col;
                    float xr = fx ? ((const float*)xres)[xi]
                                  : (float)((const bf16*)xres)[xi];
                    v = s * v + os * xr;
                    v = fmaxf(v, 0.f);
                }
                size_t oi = outOff + (size_t)row * outPitch + col;
                if (fO) ((float*)out)[oi] = v; else ((bf16*)out)[oi] = (bf16)v;
            }
        }
    }
}

// ---------------------------------------------------------------------------
// Online-softmax aggregation: 1 wave/node; lane -> 2 dims; head = lane>>4.
// KEVE rows: [0:128]=ke (folded, scaled), [128:256]=ve. G overwrites Q row.
// ---------------------------------------------------------------------------
__global__ __launch_bounds__(256) void edge_agg(
    const int* __restrict__ rp, const unsigned* __restrict__ adj,
    const bf16* Q, const bf16* __restrict__ KEVE, bf16* G, int n) {
    int lane = threadIdx.x & 63;
    int node = blockIdx.x * 4 + (threadIdx.x >> 6);
    if (node >= n) return;
    unsigned qu = *(const unsigned*)(Q + (size_t)node * 128 + lane * 2);
    float q0 = bflo(qu), q1 = bfhi(qu);
    int beg = rp[node], end = rp[node + 1];
    float m = -3.4e38f, l = 0.f, a0 = 0.f, a1 = 0.f;
    for (int i = beg; i < end; ++i) {
        unsigned row = adj[i];
        const bf16* kr = KEVE + (size_t)row * 256;
        unsigned ku = *(const unsigned*)(kr + lane * 2);
        float part = q0 * bflo(ku) + q1 * bfhi(ku);
        part += __shfl_xor(part, 1);
        part += __shfl_xor(part, 2);
        part += __shfl_xor(part, 4);
        part += __shfl_xor(part, 8);      // per-head alpha on all 16 lanes
        float nm = fmaxf(m, part);
        float sc = __expf(m - nm);
        float pe = __expf(part - nm);
        unsigned vu = *(const unsigned*)(kr + 128 + lane * 2);
        l  = l  * sc + pe;
        a0 = a0 * sc + pe * bflo(vu);
        a1 = a1 * sc + pe * bfhi(vu);
        m = nm;
    }
    float inv = (end > beg) ? 1.f / l : 0.f;
    float g0 = gelu_exact(a0 * inv);
    float g1 = gelu_exact(a1 * inv);
    *(unsigned*)(G + (size_t)node * 128 + lane * 2) = f2bfbits(g0) | (f2bfbits(g1) << 16);
}

// ---------------------------------------------------------------------------
// Logits + sentinels (NaN->12345, inf->54321)
// ---------------------------------------------------------------------------
__global__ __launch_bounds__(256) void logits_k(
    const void* X, size_t xOff, const float* __restrict__ W,
    const float* __restrict__ B, void* out, int n, const int* fxp) {
    int fx = *fxp;
    int lane = threadIdx.x & 63;
    int node = blockIdx.x * 4 + (threadIdx.x >> 6);
    if (node >= n) return;
    size_t xb = xOff + (size_t)node * 128;
    int d0 = lane * 2;
    float x0 = ldx(X, xb + d0, fx), x1 = ldx(X, xb + d0 + 1, fx);
    float p0 = x0 * W[d0 * 3 + 0] + x1 * W[d0 * 3 + 3];
    float p1 = x0 * W[d0 * 3 + 1] + x1 * W[d0 * 3 + 4];
    float p2 = x0 * W[d0 * 3 + 2] + x1 * W[d0 * 3 + 5];
    for (int off = 1; off < 64; off <<= 1) {
        p0 += __shfl_xor(p0, off);
        p1 += __shfl_xor(p1, off);
        p2 += __shfl_xor(p2, off);
    }
    if (lane == 0) {
        p0 += B[0]; p1 += B[1]; p2 += B[2];
        if (p0 != p0) p0 = 12345.f; else if (fabsf(p0) > 1e30f) p0 = 54321.f;
        if (p1 != p1) p1 = 12345.f; else if (fabsf(p1) > 1e30f) p1 = 54321.f;
        if (p2 != p2) p2 = 12345.f; else if (fabsf(p2) > 1e30f) p2 = 54321.f;
        size_t ob = (size_t)node * 3;
        if (fx) {
            ((float*)out)[ob] = p0; ((float*)out)[ob + 1] = p1; ((float*)out)[ob + 2] = p2;
        } else {
            ((bf16*)out)[ob] = (bf16)p0; ((bf16*)out)[ob + 1] = (bf16)p1;
            ((bf16*)out)[ob + 2] = (bf16)p2;
        }
    }
}

// ---------------------------------------------------------------------------

extern "C" void kernel_launch(void* const* d_in, const int* in_sizes, int n_in,
                              void* d_out, int out_size, void* d_ws, size_t ws_size,
                              hipStream_t stream) {
    (void)n_in; (void)out_size; (void)ws_size;

    const void* x_in[3] = {d_in[0], d_in[1], d_in[2]};
    const int* ei[4] = {(const int*)d_in[3], (const int*)d_in[4],
                        (const int*)d_in[5], (const int*)d_in[6]};

    // ---- workspace carve (~187 MB) ----
    char* p = (char*)d_ws;
    auto alloc = [&](size_t b) { char* r = p; p += (b + 255) & ~(size_t)255; return r; };
    bf16*  QG    = (bf16*)alloc(300000ull * 128 * 2);   // Q all types, then G in place
    bf16*  KEVE  = (bf16*)alloc(200000ull * 256 * 2);   // per-dst-type, reused
    bf16*  WqT   = (bf16*)alloc(2ull * 3 * 16384 * 2);
    bf16*  WaT   = (bf16*)alloc(2ull * 3 * 16384 * 2);
    bf16*  WkvT  = (bf16*)alloc(2ull * 8 * 16384 * 2);
    float* BKV   = (float*)alloc(2ull * 1024 * 4);
    float* qbC   = (float*)alloc(2ull * 384 * 4);
    float* abC   = (float*)alloc(2ull * 384 * 4);
    float* skipC = (float*)alloc(2ull * 3 * 4);
    float* linwC = (float*)alloc(384ull * 4);
    float* linbC = (float*)alloc(3ull * 4);
    int*   flags = (int*)alloc(2ull * 4);               // [0]=fx, [1]=fw
    int* counts  = (int*)alloc(300000ull * 4);
    int* rowptr  = (int*)alloc(300003ull * 4);
    int* cursor  = (int*)alloc(300000ull * 4);
    unsigned* adj = (unsigned*)alloc(800000ull * 4);
    int* bsum    = (int*)alloc(3ull * 256 * 4);

    int* fxp = flags;      // x / output dtype
    int* fwp = flags + 1;  // weight dtype

    const int Ns[3]    = {N0T, N1T, N2T};
    const int baseN[3] = {0, 100000, 250000};
    const int stab[4]  = {1, 2, 0, 0};
    const int tot[3]   = {400000, 200000, 200000};
    const int lbase[4] = {0, 150000, 0, 0};
    const int det[3][2] = {{0, 1}, {2, -1}, {3, -1}};
    int* cn[3] = {counts, counts + 100000, counts + 250000};
    int* rp[3] = {rowptr, rowptr + 100001, rowptr + 250002};
    int* cu[3] = {cursor, cursor + 100000, cursor + 250000};
    unsigned* aj[3] = {adj, adj + 400000, adj + 600000};
    const size_t dxsOff[3] = {300000ull, 13100000ull, 32300000ull};

    // ---- dtype detection ----
    detect_k<<<1, 256, 0, stream>>>(d_in[0], fxp);
    detect_k<<<1, 256, 0, stream>>>(d_in[7], fwp);

    // ---- weight prep (dict vs signature order adaptive) ----
    int i_skip[2];
    for (int L = 0; L < 2; ++L) {
        int b = 7 + 12 * L;
        bool sig = (in_sizes[b + 1] == 384);  // sig: kw,kb,qw,qb,vw,vb,aw,ab
        int ikw, iqw, ivw, iaw, ikb, iqb, ivb, iab;
        if (sig) { ikw = b; ikb = b + 1; iqw = b + 2; iqb = b + 3;
                   ivw = b + 4; ivb = b + 5; iaw = b + 6; iab = b + 7; }
        else     { ikw = b; iqw = b + 1; ivw = b + 2; iaw = b + 3;
                   ikb = b + 4; iqb = b + 5; ivb = b + 6; iab = b + 7; }
        i_skip[L] = b + 11;
        transpose128f<<<192, 256, 0, stream>>>(d_in[iqw], WqT + (size_t)L * 49152, fwp);
        transpose128f<<<192, 256, 0, stream>>>(d_in[iaw], WaT + (size_t)L * 49152, fwp);
        prep_kv<<<512, 256, 0, stream>>>(d_in[ikw], d_in[ivw], d_in[b + 8], d_in[b + 9],
                                         d_in[b + 10], WkvT + (size_t)L * 131072, fwp);
        prep_kvbias<<<4, 256, 0, stream>>>(d_in[ikb], d_in[ivb], d_in[b + 8], d_in[b + 9],
                                           d_in[b + 10], BKV + (size_t)L * 1024, fwp);
        conv_f32_k<<<2, 256, 0, stream>>>(d_in[iqb], qbC + L * 384, 384, fwp);
        conv_f32_k<<<2, 256, 0, stream>>>(d_in[iab], abC + L * 384, 384, fwp);
        conv_f32_k<<<1, 256, 0, stream>>>(d_in[i_skip[L]], skipC + L * 3, 3, fwp);
    }
    conv_f32_k<<<2, 256, 0, stream>>>(d_in[31], linwC, 384, fwp);
    conv_f32_k<<<1, 256, 0, stream>>>(d_in[32], linbC, 3, fwp);

    // ---- CSR build ----
    zero_i32<<<1172, 256, 0, stream>>>(counts, 300000);
    hist_k<<<3125, 256, 0, stream>>>(ei[0], ei[1], ei[2], ei[3], cn[0], cn[1], cn[2]);
    for (int t = 0; t < 3; ++t) {
        int nb = (Ns[t] + 2047) / 2048;
        scan1<<<nb, 256, 0, stream>>>(cn[t], Ns[t], rp[t], bsum + t * 256);
        scan2<<<1, 256, 0, stream>>>(bsum + t * 256, nb);
        scan3<<<(Ns[t] + 255) / 256, 256, 0, stream>>>(rp[t], bsum + t * 256, cu[t], Ns[t], tot[t]);
    }
    fill_k<<<3125, 256, 0, stream>>>(ei[0], ei[1], ei[2], ei[3],
                                     cu[0], cu[1], cu[2], aj[0], aj[1], aj[2]);

    // ---- two HGT layers ----
    for (int L = 0; L < 2; ++L) {
        // x inputs: L=0 -> d_in (offset 0); L=1 -> d_out xs slots
        const void* xp[3]; size_t xo[3];
        for (int t = 0; t < 3; ++t) {
            xp[t] = L ? (const void*)d_out : x_in[t];
            xo[t] = L ? dxsOff[t] : 0;
        }

        // Q projections (all types) -> QG canonical
        for (int t = 0; t < 3; ++t)
            gemm128<<<(Ns[t] + 63) / 64, 256, 0, stream>>>(
                xp[t], xo[t], 1, Ns[t],
                WqT + ((size_t)L * 3 + t) * 16384, qbC + L * 384 + t * 128,
                QG, (size_t)baseN[t] * 128, 128, 0, 0, nullptr, 0, nullptr, fxp);

        // per dst type: KV GEMMs into KEVE, then gather-aggregate (G over Q)
        for (int t = 0; t < 3; ++t) {
            for (int s = 0; s < 2; ++s) {
                int e = det[t][s];
                if (e < 0) break;
                int st = stab[e];
                for (int kind = 0; kind < 2; ++kind)
                    gemm128<<<(Ns[st] + 63) / 64, 256, 0, stream>>>(
                        xp[st], xo[st], 1, Ns[st],
                        WkvT + (((size_t)L * 4 + e) * 2 + kind) * 16384,
                        BKV + (size_t)L * 1024 + (e * 2 + kind) * 128,
                        KEVE, (size_t)lbase[e] * 256 + kind * 128, 256, 0, 0,
                        nullptr, 0, nullptr, fxp);
            }
            edge_agg<<<(Ns[t] + 3) / 4, 256, 0, stream>>>(
                rp[t], aj[t], QG + (size_t)baseN[t] * 128, KEVE,
                QG + (size_t)baseN[t] * 128, Ns[t]);
        }

        // output projections + skip + relu -> d_out xs (in-place for L=1)
        for (int t = 0; t < 3; ++t)
            gemm128<<<(Ns[t] + 63) / 64, 256, 0, stream>>>(
                QG, (size_t)baseN[t] * 128, 0, Ns[t],
                WaT + ((size_t)L * 3 + t) * 16384, abC + L * 384 + t * 128,
                d_out, dxsOff[t], 128, 1, 1, xp[t], xo[t], skipC + L * 3 + t, fxp);
    }

    // ---- logits head ----
    logits_k<<<25000, 256, 0, stream>>>(d_out, dxsOff[0], linwC, linbC, d_out, N0T, fxp);
}